// Round 1
// baseline (369.406 us; speedup 1.0000x reference)
//
#include <hip/hip_runtime.h>
#include <hip/hip_bf16.h>

// Shapes fixed by the reference: B=8, T=2048, D=1024.
#define BB 8
#define TT 2048
#define DD 1024

typedef __attribute__((ext_vector_type(8))) short short8;
typedef __attribute__((ext_vector_type(4))) float f32x4;
typedef __attribute__((ext_vector_type(4))) unsigned short u16x4;

__device__ inline void gload_lds16(const void* g, void* l) {
    // async global->LDS, width 16B: dest = wave-uniform base + lane*16
    __builtin_amdgcn_global_load_lds((const __attribute__((address_space(1))) void*)g,
                                     (__attribute__((address_space(3))) void*)l, 16, 0, 0);
}

#define VMW4 asm volatile("s_waitcnt vmcnt(4)" ::: "memory")
#define VMW0 asm volatile("s_waitcnt vmcnt(0)" ::: "memory")
#define BARX() __builtin_amdgcn_s_barrier()

// 16 MFMAs: one nf-pair x all 8 mf (one C-quadrant of the wave tile, K=32)
#define MM_PAIR(NF0)                                                          \
    do {                                                                      \
        __builtin_amdgcn_s_setprio(1);                                        \
        _Pragma("unroll")                                                     \
        for (int mf = 0; mf < 8; mf++) {                                      \
            acc[mf][NF0] = __builtin_amdgcn_mfma_f32_16x16x32_bf16(           \
                aF[mf], bF[NF0], acc[mf][NF0], 0, 0, 0);                      \
            acc[mf][NF0 + 1] = __builtin_amdgcn_mfma_f32_16x16x32_bf16(       \
                aF[mf], bF[NF0 + 1], acc[mf][NF0 + 1], 0, 0, 0);              \
        }                                                                     \
        __builtin_amdgcn_s_setprio(0);                                        \
    } while (0)

// ---------------------------------------------------------------------------
// 256x256-tile, BK=64, 8-wave (2Mx4N), 8-phase pipelined bf16 MFMA GEMM core.
// LDS 128 KiB: 2 buffers x {A,B} x 2 kh-planes (256 rows x 32 cols bf16 each).
// Planes are LDS-contiguous => each staging slab is a linear global_load_lds
// target; XOR swizzle (chunk ^= (row>>1)&3) applied on the GLOBAL source and
// undone on the ds_read side (m173 pattern) => conflict-free b128 frag reads.
// Counted vmcnt(4) gates (never 0 mid-loop): per-wave ledger = 2 loads/slab,
// 8 outstanding max, oldest-4 completion == the slabs the next phases read.
// MODE 0: C[CT] = scale*acc   MODE 1: C=exp(scale*acc) causal + rowsum atomics
// MODE 2: C[f32] = acc / rs[row]
// ---------------------------------------------------------------------------
template<int MODE, typename CT>
__device__ __forceinline__ void gemm_core256(
    const __hip_bfloat16* __restrict__ A,
    const __hip_bfloat16* __restrict__ Bt,
    void* __restrict__ Cbase,
    int lda, int ldb, int ldc,
    int m0, int n0, int kmax,
    float scale, float* __restrict__ rs)
{
    __shared__ __align__(16) char lsA[65536];   // [buf][kh] 16 KiB planes
    __shared__ __align__(16) char lsB[65536];

    const int t   = threadIdx.x;     // 0..511
    const int w   = t >> 6;          // wave 0..7
    const int l   = t & 63;
    const int q   = l >> 4;
    const int i16 = l & 15;
    const int wy  = w >> 2;          // wave M-offset 128*wy
    const int wx  = w & 3;           // wave N-offset 64*wx

    // staging: plane byte off = w*2048 + j*1024 + l*16 -> row=off>>6, slot=(off>>4)&3
    // source chunk = slot ^ ((row>>1)&3)
    const int r0  = w * 32 + (l >> 2);
    const int r1  = r0 + 16;
    const int cg0 = (l & 3) ^ ((r0 >> 1) & 3);
    const int cg1 = (l & 3) ^ ((r1 >> 1) & 3);
    const __hip_bfloat16* gA0 = A  + (size_t)(m0 + r0) * lda + cg0 * 8;
    const __hip_bfloat16* gA1 = A  + (size_t)(m0 + r1) * lda + cg1 * 8;
    const __hip_bfloat16* gB0 = Bt + (size_t)(n0 + r0) * ldb + cg0 * 8;
    const __hip_bfloat16* gB1 = Bt + (size_t)(n0 + r1) * ldb + cg1 * 8;

    // frag reads: 64B rows, chunk = q ^ ((row>>1)&3) -> 2-way max (free)
    const int swz  = (q ^ ((i16 >> 1) & 3)) << 4;
    const int offA = (wy * 128 + i16) * 64 + swz;   // + mf*1024
    const int offB = (wx * 64  + i16) * 64 + swz;   // + nf*1024

    f32x4 acc[8][4];
#pragma unroll
    for (int mf = 0; mf < 8; mf++)
#pragma unroll
        for (int nf = 0; nf < 4; nf++) acc[mf][nf] = f32x4{0.f, 0.f, 0.f, 0.f};

    short8 aF[8], bF[4];
    const int NT = kmax >> 6;

    // prologue: tile0 = A.kh0, B.kh0, A.kh1, B.kh1 (oldest 4 = kh0 slabs)
    {
        char* dA = lsA + (w << 11);
        char* dB = lsB + (w << 11);
        gload_lds16(gA0, dA);            gload_lds16(gA1, dA + 1024);
        gload_lds16(gB0, dB);            gload_lds16(gB1, dB + 1024);
        gload_lds16(gA0 + 32, dA + 16384); gload_lds16(gA1 + 32, dA + 16384 + 1024);
        gload_lds16(gB0 + 32, dB + 16384); gload_lds16(gB1 + 32, dB + 16384 + 1024);
    }
    VMW4; BARX();                        // tile0 kh0 resident

    int buf = 0;
    for (int tt = 0; tt < NT; ++tt, buf ^= 1) {
        const bool nx = (tt + 1) < NT;
        const int  kn = (tt + 1) << 6;
        char* sA = lsA + (buf ? 32768 : 0);
        char* sB = lsB + (buf ? 32768 : 0);
        char* dA = lsA + (buf ? 0 : 32768) + (w << 11);
        char* dB = lsB + (buf ? 0 : 32768) + (w << 11);

        // P0: kh0 frags; stage A.kh0(t+1)
#pragma unroll
        for (int mf = 0; mf < 8; mf++)
            aF[mf] = *(const short8*)(sA + offA + mf * 1024);
#pragma unroll
        for (int nf = 0; nf < 4; nf++)
            bF[nf] = *(const short8*)(sB + offB + nf * 1024);
        if (nx) { gload_lds16(gA0 + kn, dA); gload_lds16(gA1 + kn, dA + 1024); }
        BARX();
        MM_PAIR(0);
        BARX();
        // P1: stage B.kh0(t+1); gate this tile's kh1 (allow 4 newest in flight)
        if (nx) { gload_lds16(gB0 + kn, dB); gload_lds16(gB1 + kn, dB + 1024); }
        BARX();
        MM_PAIR(2);
        if (nx) { VMW4; } else { VMW0; }
        BARX();
        // P2: kh1 frags; stage A.kh1(t+1)
#pragma unroll
        for (int mf = 0; mf < 8; mf++)
            aF[mf] = *(const short8*)(sA + 16384 + offA + mf * 1024);
#pragma unroll
        for (int nf = 0; nf < 4; nf++)
            bF[nf] = *(const short8*)(sB + 16384 + offB + nf * 1024);
        if (nx) { gload_lds16(gA0 + kn + 32, dA + 16384);
                  gload_lds16(gA1 + kn + 32, dA + 16384 + 1024); }
        BARX();
        MM_PAIR(0);
        BARX();
        // P3: stage B.kh1(t+1); gate next tile's kh0
        if (nx) { gload_lds16(gB0 + kn + 32, dB + 16384);
                  gload_lds16(gB1 + kn + 32, dB + 16384 + 1024); }
        BARX();
        MM_PAIR(2);
        if (nx) { VMW4; }
        BARX();
    }

    // epilogue: C/D layout col = i16, row = q*4 + reg
    if constexpr (MODE == 0) {
        CT* C = (CT*)Cbase;
#pragma unroll
        for (int mf = 0; mf < 8; mf++) {
            int rbase = m0 + wy * 128 + mf * 16 + q * 4;
#pragma unroll
            for (int nf = 0; nf < 4; nf++) {
                int col = n0 + wx * 64 + nf * 16 + i16;
#pragma unroll
                for (int r = 0; r < 4; r++) {
                    float v = acc[mf][nf][r] * scale;
                    if constexpr (sizeof(CT) == 2)
                        C[(size_t)(rbase + r) * ldc + col] = (CT)__float2bfloat16(v);
                    else
                        *((float*)&C[(size_t)(rbase + r) * ldc + col]) = v;
                }
            }
        }
    } else if constexpr (MODE == 1) {
        __hip_bfloat16* C = (__hip_bfloat16*)Cbase;
#pragma unroll
        for (int mf = 0; mf < 8; mf++) {
            int rbase = m0 + wy * 128 + mf * 16 + q * 4;
#pragma unroll
            for (int r = 0; r < 4; r++) {
                int row = rbase + r;
                float part = 0.f, pv[4];
#pragma unroll
                for (int nf = 0; nf < 4; nf++) {
                    int col = n0 + wx * 64 + nf * 16 + i16;
                    float e = (col <= row) ? __expf(acc[mf][nf][r] * scale) : 0.f;
                    pv[nf] = e;
                    part += e;
                }
                part += __shfl_xor(part, 1, 64);
                part += __shfl_xor(part, 2, 64);
                part += __shfl_xor(part, 4, 64);
                part += __shfl_xor(part, 8, 64);
                if (i16 == 0) atomicAdd(&rs[row], part);
#pragma unroll
                for (int nf = 0; nf < 4; nf++) {
                    int col = n0 + wx * 64 + nf * 16 + i16;
                    C[(size_t)row * ldc + col] = __float2bfloat16(pv[nf]);
                }
            }
        }
    } else {
        float* C = (float*)Cbase;
#pragma unroll
        for (int mf = 0; mf < 8; mf++) {
            int rbase = m0 + wy * 128 + mf * 16 + q * 4;
#pragma unroll
            for (int r = 0; r < 4; r++) {
                int row = rbase + r;
                float inv = 1.f / rs[row];
#pragma unroll
                for (int nf = 0; nf < 4; nf++) {
                    int col = n0 + wx * 64 + nf * 16 + i16;
                    C[(size_t)row * ldc + col] = acc[mf][nf][r] * inv;
                }
            }
        }
    }
}

// ---------------------------------------------------------------------------
// Fused projections: z=0,1 -> K,Q = x @ W{k,q} (64 m-tiles x 4 n-tiles);
// z=2 -> vT2 = Wv^T @ x^T (4 x 64). 256 blocks/z, bijective XCD swizzle:
// XCD d gets a contiguous 1/8 chunk => B panels (2 MiB) L2-resident per XCD.
// ---------------------------------------------------------------------------
__global__ __launch_bounds__(512, 2) void proj3_8ph(
    const __hip_bfloat16* __restrict__ xb,
    const __hip_bfloat16* __restrict__ wt,
    __hip_bfloat16* __restrict__ kq,
    __hip_bfloat16* __restrict__ vT2)
{
    const int z = blockIdx.y;
    const int x = blockIdx.x;
    const int swz = (x & 7) * 32 + (x >> 3);   // nwg=256, bijective %8 chunks
    const __hip_bfloat16 *A, *Bt;
    void* C;
    int ldc, m0, n0;
    if (z < 2) {
        A = xb; Bt = wt + z * 1048576; C = kq + (size_t)z * 16777216;
        ldc = 1024; m0 = (swz >> 2) * 256; n0 = (swz & 3) * 256;
    } else {
        A = wt + 2 * 1048576; Bt = xb; C = vT2;
        ldc = 16384; m0 = (swz & 3) * 256; n0 = (swz >> 2) * 256;
    }
    gemm_core256<0, __hip_bfloat16>(A, Bt, C, 1024, 1024, ldc, m0, n0, 1024, 1.0f, nullptr);
}

// ---------------------------------------------------------------------------
// S = exp(Q K^T / 32) causal, bf16; rowsums -> rsum. Grid (8 n,8 m,g).
// XCD = blockIdx.x; parity swizzle n_eff = (y+z)&1 ? x : 7-x gives every XCD
// exactly 36 working blocks (sum_y 4*[7-x<=y] + 4*[x<=y] = 36).
// ---------------------------------------------------------------------------
__global__ __launch_bounds__(512, 2) void sgemm256(
    const __hip_bfloat16* __restrict__ qq,
    const __hip_bfloat16* __restrict__ kk,
    __hip_bfloat16* __restrict__ Pp,
    float* __restrict__ rsum)
{
    const int z = blockIdx.z;
    const int y = blockIdx.y;                                   // m-tile
    const int ne = ((y + z) & 1) ? blockIdx.x : 7 - blockIdx.x; // n-tile
    if (ne > y) return;                                         // causal skip
    gemm_core256<1, __hip_bfloat16>(
        qq + (size_t)z * 2097152, kk + (size_t)z * 2097152,
        Pp + (size_t)z * 4194304,
        1024, 1024, 2048, y * 256, ne * 256, 1024, 0.03125f,
        rsum + (size_t)z * TT);
}

// ---------------------------------------------------------------------------
// out = (P' @ V) / rowsum, causal K-stop kmax = m0+256. Grid (4 n,8 m,g) =
// 256 blocks exactly (1/CU): makespan = longest block (y=7). K>row reads the
// zero-masked diagonal-tile region of P' (written 0 by MODE 1).
// ---------------------------------------------------------------------------
__global__ __launch_bounds__(512, 2) void pvgemm256(
    const __hip_bfloat16* __restrict__ Pp,
    const __hip_bfloat16* __restrict__ vT2,
    float* __restrict__ out,
    float* __restrict__ rsum)
{
    const int z = blockIdx.z;
    const int y = blockIdx.y;    // m-tile 0..7
    const int x = blockIdx.x;    // n-tile 0..3
    gemm_core256<2, float>(
        Pp + (size_t)z * 4194304, vT2 + (size_t)z * 2048,
        out + (size_t)z * 2097152,
        2048, 16384, 1024, y * 256, x * 256, (y + 1) * 256, 1.0f,
        rsum + (size_t)z * TT);
}

// ---------------------------------------------------------------------------
// x (fp32) -> bf16, 4 elems/thread vectorized
// ---------------------------------------------------------------------------
__global__ __launch_bounds__(256) void cvt_x(const float* __restrict__ in,
                                             unsigned short* __restrict__ out)
{
    size_t i = ((size_t)blockIdx.x * 256 + threadIdx.x) * 4;
    float4 f = *(const float4*)(in + i);
    union { u16x4 u; __hip_bfloat16 h[4]; } o;
    o.h[0] = __float2bfloat16(f.x);
    o.h[1] = __float2bfloat16(f.y);
    o.h[2] = __float2bfloat16(f.z);
    o.h[3] = __float2bfloat16(f.w);
    *(u16x4*)(out + i) = o.u;
}

// ---------------------------------------------------------------------------
// W (DxD fp32, row-major [c][h]) -> Wt (bf16, [h][c]); z selects Wk/Wq/Wv
// ---------------------------------------------------------------------------
__global__ __launch_bounds__(256) void transpose_cvt_w(
    const float* __restrict__ Wk, const float* __restrict__ Wq,
    const float* __restrict__ Wv, __hip_bfloat16* __restrict__ Wt)
{
    const float* W = blockIdx.z == 0 ? Wk : (blockIdx.z == 1 ? Wq : Wv);
    __hip_bfloat16* o = Wt + (size_t)blockIdx.z * DD * DD;
    int h0 = blockIdx.x * 32, c0 = blockIdx.y * 32;
    __shared__ float tl[32][33];
    int tx = threadIdx.x, ty = threadIdx.y;
#pragma unroll
    for (int k = 0; k < 4; k++)
        tl[ty + 8 * k][tx] = W[(size_t)(c0 + ty + 8 * k) * DD + h0 + tx];
    __syncthreads();
#pragma unroll
    for (int k = 0; k < 4; k++)
        o[(size_t)(h0 + ty + 8 * k) * DD + c0 + tx] = __float2bfloat16(tl[tx][ty + 8 * k]);
}

// ---------------------------------------------------------------------------
extern "C" void kernel_launch(void* const* d_in, const int* in_sizes, int n_in,
                              void* d_out, int out_size, void* d_ws, size_t ws_size,
                              hipStream_t stream)
{
    const float* x  = (const float*)d_in[0];
    const float* Wk = (const float*)d_in[1];
    const float* Wq = (const float*)d_in[2];
    const float* Wv = (const float*)d_in[3];
    float* out = (float*)d_out;

    // workspace layout (bytes):
    //   k    @ 0           : 33,554,432 B bf16
    //   q    @  33,554,432 : 33,554,432 B bf16
    //   vT2  @  67,108,864 : 33,554,432 B bf16 [d][b*T+t]
    //   wt   @ 100,663,296 :  6,291,456 B bf16 [k,q,v]; dead after proj ->
    //   rsum @ 100,663,296 : g*8,192 B fp32 row sums (overlays wt)
    //   xb   @ 106,954,752 : 33,554,432 B bf16; dead after proj ->
    //   P'   @ 106,954,752 : g*8,388,608 B bf16 exp(S) (overlays xb)
    char* ws = (char*)d_ws;
    __hip_bfloat16* kk   = (__hip_bfloat16*)ws;
    __hip_bfloat16* qq   = (__hip_bfloat16*)(ws + 33554432);
    __hip_bfloat16* vT2  = (__hip_bfloat16*)(ws + 67108864);
    __hip_bfloat16* wt   = (__hip_bfloat16*)(ws + 100663296);
    float*          rsum = (float*)         (ws + 100663296);
    __hip_bfloat16* xb   = (__hip_bfloat16*)(ws + 106954752);
    __hip_bfloat16* Pp   = (__hip_bfloat16*)(ws + 106954752);

    // batch group size (deterministic from ws_size): g=8 needs 174,063,616 B
    int g = (ws_size >= 106954752ull + 8ull * 8388608ull) ? 8 : 4;

    // 1. convert inputs to bf16 (W transposed to B^T layout)
    cvt_x<<<16384, 256, 0, stream>>>(x, (unsigned short*)xb);
    transpose_cvt_w<<<dim3(32, 32, 3), dim3(32, 8), 0, stream>>>(Wk, Wq, Wv, wt);

    // 2. K,Q,vT in one dispatch: 768 uniform 256^2 blocks = 3 full rounds
    proj3_8ph<<<dim3(256, 3), 512, 0, stream>>>(xb, wt, kk, vT2);

    // 3..4 per batch group
    for (int g0 = 0; g0 < BB; g0 += g) {
        hipMemsetAsync(rsum, 0, (size_t)g * TT * 4, stream);

        sgemm256<<<dim3(8, 8, g), 512, 0, stream>>>(
            qq + (size_t)g0 * 2097152, kk + (size_t)g0 * 2097152, Pp, rsum);

        pvgemm256<<<dim3(4, 8, g), 512, 0, stream>>>(
            Pp, vT2 + (size_t)g0 * 2048, out + (size_t)g0 * 2097152, rsum);
    }
}